// Round 1
// baseline (7075.143 us; speedup 1.0000x reference)
//
#include <hip/hip_runtime.h>

#define N_NODES 20000
#define S_COLS  4096
#define E_EDGES 640000
#define D_DIM   256

// ---------------------------------------------------------------------------
// K0: phi[j][d] = b2[d] + sum_k relu(j*w1[k] + b1[k]) * w2[k][d]
// grid = S_COLS blocks x 256 threads (one block per j, one thread per d)
// ---------------------------------------------------------------------------
__global__ void phi_kernel(const float* __restrict__ w1, const float* __restrict__ b1,
                           const float* __restrict__ w2, const float* __restrict__ b2,
                           float* __restrict__ phi) {
    int j = blockIdx.x;
    int d = threadIdx.x;
    float jf = (float)j;
    float acc = b2[d];
#pragma unroll
    for (int k = 0; k < 16; ++k) {
        float t = fmaxf(jf * w1[k] + b1[k], 0.f);
        acc += t * w2[k * D_DIM + d];
    }
    phi[j * D_DIM + d] = acc;
}

// ---------------------------------------------------------------------------
// K1: h0[i] = mean over nonzero columns j of row i of phi[j]
// One block (256 threads) per row. Phase A: scan row (float4 loads), push
// nonzero column indices into an LDS list. Phase B: thread d sums phi[j][d].
// Mean count ~82 (binomial(4096, 0.02)); 1024-entry list is > +100 sigma.
// ---------------------------------------------------------------------------
__global__ void h0_kernel(const float* __restrict__ init_m, const float* __restrict__ phi,
                          float* __restrict__ h) {
    __shared__ int list[1024];
    __shared__ int count;
    int i = blockIdx.x;
    int t = threadIdx.x;
    if (t == 0) count = 0;
    __syncthreads();
    const float4* rowp = (const float4*)(init_m + (size_t)i * S_COLS);
#pragma unroll
    for (int p = 0; p < 4; ++p) {
        int v4 = t + p * 256;          // float4 index within the row (0..1023)
        float4 v = rowp[v4];
        int jbase = v4 * 4;
        if (v.x != 0.f) { int idx = atomicAdd(&count, 1); list[idx] = jbase;     }
        if (v.y != 0.f) { int idx = atomicAdd(&count, 1); list[idx] = jbase + 1; }
        if (v.z != 0.f) { int idx = atomicAdd(&count, 1); list[idx] = jbase + 2; }
        if (v.w != 0.f) { int idx = atomicAdd(&count, 1); list[idx] = jbase + 3; }
    }
    __syncthreads();
    int cnt = count;
    float acc = 0.f;
    for (int q = 0; q < cnt; ++q) {
        acc += phi[list[q] * D_DIM + t];   // coalesced 1KB read per iter; list[q] is LDS broadcast
    }
    h[(size_t)i * D_DIM + t] = acc / fmaxf((float)cnt, 1.f);
}

// ---------------------------------------------------------------------------
// K2: scatter — agg[col[e]] += h[row[e]] * attr[e]
// One wave per edge (64 lanes x float4 = 256 floats), wave-stride loop.
// ---------------------------------------------------------------------------
__global__ void scatter_kernel(const float* __restrict__ h, const int* __restrict__ eidx,
                               const float* __restrict__ attr, float* __restrict__ agg) {
    int gid   = blockIdx.x * blockDim.x + threadIdx.x;
    int wave  = gid >> 6;
    int lane  = threadIdx.x & 63;
    int nwav  = (gridDim.x * blockDim.x) >> 6;
    for (int e = wave; e < E_EDGES; e += nwav) {
        int r = eidx[e];
        int c = eidx[E_EDGES + e];
        float a = attr[e];
        float4 v = ((const float4*)(h + (size_t)r * D_DIM))[lane];
        float* dst = agg + (size_t)c * D_DIM + lane * 4;
        atomicAdd(dst + 0, v.x * a);
        atomicAdd(dst + 1, v.y * a);
        atomicAdd(dst + 2, v.z * a);
        atomicAdd(dst + 3, v.w * a);
    }
}

// ---------------------------------------------------------------------------
// K3: C = relu(A @ B), A [M x 256], B [256 x 256].
// 64x64 tile per 256-thread block, 4x4 register tile per thread, BK=16.
// As stored k-major (transposed) so the inner loop does float4 LDS reads.
// ---------------------------------------------------------------------------
__global__ void gemm_relu_kernel(const float* __restrict__ A, const float* __restrict__ B,
                                 float* __restrict__ C, int M) {
    __shared__ float As[16][64];
    __shared__ float Bs[16][64];
    int t  = threadIdx.x;
    int tx = t & 15, ty = t >> 4;
    int bm = blockIdx.x * 64;
    int bn = blockIdx.y * 64;
    float acc[4][4] = {};
    for (int k0 = 0; k0 < 256; k0 += 16) {
        // A tile: 64 rows x 16 k; thread t loads (row = p*16 + t/16, k = t%16)
#pragma unroll
        for (int p = 0; p < 4; ++p) {
            int row = p * 16 + ty;
            int m   = bm + row;
            As[tx][row] = (m < M) ? A[(size_t)m * 256 + k0 + tx] : 0.f;
        }
        // B tile: 16 k x 64 n; thread t loads (k = p*4 + t/64, n = t%64)
#pragma unroll
        for (int p = 0; p < 4; ++p) {
            int kk = p * 4 + (t >> 6);
            int n  = t & 63;
            Bs[kk][n] = B[(size_t)(k0 + kk) * 256 + bn + n];
        }
        __syncthreads();
#pragma unroll
        for (int kk = 0; kk < 16; ++kk) {
            float4 a4 = *(const float4*)&As[kk][ty * 4];
            float4 b4 = *(const float4*)&Bs[kk][tx * 4];
            float av[4] = {a4.x, a4.y, a4.z, a4.w};
            float bv[4] = {b4.x, b4.y, b4.z, b4.w};
#pragma unroll
            for (int i = 0; i < 4; ++i)
#pragma unroll
                for (int j = 0; j < 4; ++j)
                    acc[i][j] += av[i] * bv[j];
        }
        __syncthreads();
    }
#pragma unroll
    for (int i = 0; i < 4; ++i) {
        int m = bm + ty * 4 + i;
        if (m < M) {
            float4 o;
            o.x = fmaxf(acc[i][0], 0.f);
            o.y = fmaxf(acc[i][1], 0.f);
            o.z = fmaxf(acc[i][2], 0.f);
            o.w = fmaxf(acc[i][3], 0.f);
            *(float4*)(C + (size_t)m * 256 + bn + tx * 4) = o;
        }
    }
}

extern "C" void kernel_launch(void* const* d_in, const int* in_sizes, int n_in,
                              void* d_out, int out_size, void* d_ws, size_t ws_size,
                              hipStream_t stream) {
    const float* init_m = (const float*)d_in[0];
    const int*   eidx   = (const int*)  d_in[1];
    const float* attr   = (const float*)d_in[2];
    const float* w1     = (const float*)d_in[3];
    const float* b1     = (const float*)d_in[4];
    const float* w2     = (const float*)d_in[5];
    const float* b2     = (const float*)d_in[6];
    const float* Wm     = (const float*)d_in[7];
    float* out = (float*)d_out;

    char* ws = (char*)d_ws;
    float* phi    = (float*)ws;                               // 4096*256*4   = 4,194,304 B
    float* hbuf   = (float*)(ws + 4194304);                   // 20000*256*4  = 20,480,000 B
    float* aggbuf = (float*)(ws + 4194304 + 20480000);        // 20,480,000 B  (total ~45.2 MB)

    phi_kernel<<<S_COLS, 256, 0, stream>>>(w1, b1, w2, b2, phi);
    h0_kernel<<<N_NODES, 256, 0, stream>>>(init_m, phi, hbuf);

    for (int it = 0; it < 3; ++it) {
        hipMemsetAsync(aggbuf, 0, (size_t)N_NODES * D_DIM * sizeof(float), stream);
        scatter_kernel<<<1024, 256, 0, stream>>>(hbuf, eidx, attr, aggbuf);
        float* dst = (it == 2) ? out : hbuf;
        dim3 grid((N_NODES + 63) / 64, 4);
        gemm_relu_kernel<<<grid, 256, 0, stream>>>(aggbuf, Wm, dst, N_NODES);
    }
}

// Round 2
// 1028.759 us; speedup vs baseline: 6.8774x; 6.8774x over previous
//
#include <hip/hip_runtime.h>

#define N_NODES 20000
#define S_COLS  4096
#define E_EDGES 640000
#define D_DIM   256

// ---------------------------------------------------------------------------
// K0: phi[j][d] = b2[d] + sum_k relu(j*w1[k] + b1[k]) * w2[k][d]
// ---------------------------------------------------------------------------
__global__ void phi_kernel(const float* __restrict__ w1, const float* __restrict__ b1,
                           const float* __restrict__ w2, const float* __restrict__ b2,
                           float* __restrict__ phi) {
    int j = blockIdx.x;
    int d = threadIdx.x;
    float jf = (float)j;
    float acc = b2[d];
#pragma unroll
    for (int k = 0; k < 16; ++k) {
        float t = fmaxf(jf * w1[k] + b1[k], 0.f);
        acc += t * w2[k * D_DIM + d];
    }
    phi[j * D_DIM + d] = acc;
}

// ---------------------------------------------------------------------------
// K1: h0[i] = mean over nonzero columns j of row i of phi[j]
// One block (256 threads) per row: scan row with float4, LDS nonzero list,
// then thread d sums phi[j][d] over the list.
// ---------------------------------------------------------------------------
__global__ void h0_kernel(const float* __restrict__ init_m, const float* __restrict__ phi,
                          float* __restrict__ h) {
    __shared__ int list[1024];
    __shared__ int count;
    int i = blockIdx.x;
    int t = threadIdx.x;
    if (t == 0) count = 0;
    __syncthreads();
    const float4* rowp = (const float4*)(init_m + (size_t)i * S_COLS);
#pragma unroll
    for (int p = 0; p < 4; ++p) {
        int v4 = t + p * 256;
        float4 v = rowp[v4];
        int jbase = v4 * 4;
        if (v.x != 0.f) { int idx = atomicAdd(&count, 1); list[idx] = jbase;     }
        if (v.y != 0.f) { int idx = atomicAdd(&count, 1); list[idx] = jbase + 1; }
        if (v.z != 0.f) { int idx = atomicAdd(&count, 1); list[idx] = jbase + 2; }
        if (v.w != 0.f) { int idx = atomicAdd(&count, 1); list[idx] = jbase + 3; }
    }
    __syncthreads();
    int cnt = count;
    float acc = 0.f;
    for (int q = 0; q < cnt; ++q) {
        acc += phi[list[q] * D_DIM + t];
    }
    h[(size_t)i * D_DIM + t] = acc / fmaxf((float)cnt, 1.f);
}

// ---------------------------------------------------------------------------
// CSC build (once per launch): counting sort of edges by destination col.
// ---------------------------------------------------------------------------
__global__ void count_kernel(const int* __restrict__ eidx, int* __restrict__ cnt) {
    int e = blockIdx.x * 256 + threadIdx.x;
    if (e < E_EDGES) atomicAdd(&cnt[eidx[E_EDGES + e]], 1);
}

// Single-block exclusive scan of cnt[N] -> offs[N+1], also copies to cur[N].
// 1024 threads x 20 elements each (20480 >= 20000).
__global__ void scan_kernel(const int* __restrict__ cnt, int* __restrict__ offs,
                            int* __restrict__ cur) {
    __shared__ int sdata[1024];
    int t = threadIdx.x;
    int base = t * 20;
    int vals[20];
    int local = 0;
#pragma unroll
    for (int k = 0; k < 20; ++k) {
        int idx = base + k;
        int v = (idx < N_NODES) ? cnt[idx] : 0;
        vals[k] = local;
        local += v;
    }
    sdata[t] = local;
    __syncthreads();
    // Hillis-Steele inclusive scan over 1024 partials
    for (int off = 1; off < 1024; off <<= 1) {
        int v = (t >= off) ? sdata[t - off] : 0;
        __syncthreads();
        sdata[t] += v;
        __syncthreads();
    }
    int prefix = (t == 0) ? 0 : sdata[t - 1];
#pragma unroll
    for (int k = 0; k < 20; ++k) {
        int idx = base + k;
        if (idx < N_NODES) {
            int o = prefix + vals[k];
            offs[idx] = o;
            cur[idx]  = o;
        }
    }
    if (t == 1023) offs[N_NODES] = sdata[1023];
}

__global__ void fill_kernel(const int* __restrict__ eidx, const float* __restrict__ attr,
                            int* __restrict__ cur, int* __restrict__ src_s,
                            float* __restrict__ attr_s) {
    int e = blockIdx.x * 256 + threadIdx.x;
    if (e < E_EDGES) {
        int r = eidx[e];
        int c = eidx[E_EDGES + e];
        int pos = atomicAdd(&cur[c], 1);
        src_s[pos]  = r;
        attr_s[pos] = attr[e];
    }
}

// ---------------------------------------------------------------------------
// K2: gather — agg[c] = sum over incoming edges e of h[src[e]] * attr[e]
// One wave per destination node; lane = float4 channel group. No atomics.
// ---------------------------------------------------------------------------
__global__ void gather_kernel(const float* __restrict__ h, const int* __restrict__ offs,
                              const int* __restrict__ src_s, const float* __restrict__ attr_s,
                              float* __restrict__ agg) {
    int wave = (blockIdx.x * blockDim.x + threadIdx.x) >> 6;
    int lane = threadIdx.x & 63;
    if (wave >= N_NODES) return;
    int c  = wave;
    int e0 = offs[c], e1 = offs[c + 1];
    float4 acc = {0.f, 0.f, 0.f, 0.f};
    for (int e = e0; e < e1; ++e) {
        int   r = src_s[e];
        float a = attr_s[e];
        float4 v = ((const float4*)(h + (size_t)r * D_DIM))[lane];
        acc.x += v.x * a;
        acc.y += v.y * a;
        acc.z += v.z * a;
        acc.w += v.w * a;
    }
    ((float4*)(agg + (size_t)c * D_DIM))[lane] = acc;
}

// ---------------------------------------------------------------------------
// K3: C = relu(A @ B), A [M x 256], B [256 x 256].
// 64x64 tile / 256-thread block, 4x4 register tile, BK=16.
// ---------------------------------------------------------------------------
__global__ void gemm_relu_kernel(const float* __restrict__ A, const float* __restrict__ B,
                                 float* __restrict__ C, int M) {
    __shared__ float As[16][64];
    __shared__ float Bs[16][64];
    int t  = threadIdx.x;
    int tx = t & 15, ty = t >> 4;
    int bm = blockIdx.x * 64;
    int bn = blockIdx.y * 64;
    float acc[4][4] = {};
    for (int k0 = 0; k0 < 256; k0 += 16) {
#pragma unroll
        for (int p = 0; p < 4; ++p) {
            int row = p * 16 + ty;
            int m   = bm + row;
            As[tx][row] = (m < M) ? A[(size_t)m * 256 + k0 + tx] : 0.f;
        }
#pragma unroll
        for (int p = 0; p < 4; ++p) {
            int kk = p * 4 + (t >> 6);
            int n  = t & 63;
            Bs[kk][n] = B[(size_t)(k0 + kk) * 256 + bn + n];
        }
        __syncthreads();
#pragma unroll
        for (int kk = 0; kk < 16; ++kk) {
            float4 a4 = *(const float4*)&As[kk][ty * 4];
            float4 b4 = *(const float4*)&Bs[kk][tx * 4];
            float av[4] = {a4.x, a4.y, a4.z, a4.w};
            float bv[4] = {b4.x, b4.y, b4.z, b4.w};
#pragma unroll
            for (int i = 0; i < 4; ++i)
#pragma unroll
                for (int j = 0; j < 4; ++j)
                    acc[i][j] += av[i] * bv[j];
        }
        __syncthreads();
    }
#pragma unroll
    for (int i = 0; i < 4; ++i) {
        int m = bm + ty * 4 + i;
        if (m < M) {
            float4 o;
            o.x = fmaxf(acc[i][0], 0.f);
            o.y = fmaxf(acc[i][1], 0.f);
            o.z = fmaxf(acc[i][2], 0.f);
            o.w = fmaxf(acc[i][3], 0.f);
            *(float4*)(C + (size_t)m * 256 + bn + tx * 4) = o;
        }
    }
}

extern "C" void kernel_launch(void* const* d_in, const int* in_sizes, int n_in,
                              void* d_out, int out_size, void* d_ws, size_t ws_size,
                              hipStream_t stream) {
    const float* init_m = (const float*)d_in[0];
    const int*   eidx   = (const int*)  d_in[1];
    const float* attr   = (const float*)d_in[2];
    const float* w1     = (const float*)d_in[3];
    const float* b1     = (const float*)d_in[4];
    const float* w2     = (const float*)d_in[5];
    const float* b2     = (const float*)d_in[6];
    const float* Wm     = (const float*)d_in[7];
    float* out = (float*)d_out;

    // Workspace layout (bytes):
    char* ws = (char*)d_ws;
    float* phi     = (float*)ws;                        // 4,194,304
    float* hbuf    = (float*)(ws + 4194304);            // 20,480,000
    float* aggbuf  = (float*)(ws + 24674304);           // 20,480,000
    int*   cnt     = (int*)  (ws + 45154304);           // 80,000
    int*   offs    = (int*)  (ws + 45234304);           // 80,004
    int*   cur     = (int*)  (ws + 45314308);           // 80,000
    int*   src_s   = (int*)  (ws + 45394308);           // 2,560,000
    float* attr_s  = (float*)(ws + 47954308);           // 2,560,000  -> total 50,514,308 B

    // --- CSC build (counting sort by destination col) ---
    hipMemsetAsync(cnt, 0, (size_t)N_NODES * sizeof(int), stream);
    count_kernel<<<(E_EDGES + 255) / 256, 256, 0, stream>>>(eidx, cnt);
    scan_kernel<<<1, 1024, 0, stream>>>(cnt, offs, cur);
    fill_kernel<<<(E_EDGES + 255) / 256, 256, 0, stream>>>(eidx, attr, cur, src_s, attr_s);

    // --- Projection ---
    phi_kernel<<<S_COLS, 256, 0, stream>>>(w1, b1, w2, b2, phi);
    h0_kernel<<<N_NODES, 256, 0, stream>>>(init_m, phi, hbuf);

    // --- 3x GCN layer: gather (no atomics) + GEMM+ReLU ---
    for (int it = 0; it < 3; ++it) {
        gather_kernel<<<(N_NODES * 64 + 255) / 256, 256, 0, stream>>>(hbuf, offs, src_s, attr_s, aggbuf);
        float* dst = (it == 2) ? out : hbuf;
        dim3 grid((N_NODES + 63) / 64, 4);
        gemm_relu_kernel<<<grid, 256, 0, stream>>>(aggbuf, Wm, dst, N_NODES);
    }
}

// Round 3
// 873.848 us; speedup vs baseline: 8.0965x; 1.1773x over previous
//
#include <hip/hip_runtime.h>

#define N_NODES 20000
#define S_COLS  4096
#define E_EDGES 640000
#define D_DIM   256

typedef unsigned short bf16_t;

__device__ __forceinline__ float bf2f(bf16_t u) {
    union { unsigned int i; float f; } v; v.i = ((unsigned int)u) << 16; return v.f;
}
__device__ __forceinline__ bf16_t f2bf(float x) {   // round-to-nearest-even
    union { float f; unsigned int i; } v; v.f = x;
    unsigned int r = v.i + 0x7FFF + ((v.i >> 16) & 1);
    return (bf16_t)(r >> 16);
}

// ---------------------------------------------------------------------------
// K1: h0[i] = mean over nonzero columns j of phi[j], where
// phi[j] = b2 + relu(j*w1 + b1) @ w2  (rank-16 in j). We accumulate the
// 16-dim feature sum over nonzero j, then one 16x256 matvec:
//   h0[i] = (cnt*b2 + fsum @ w2) / max(cnt,1)
// One block per row. Phase A: float4 scan -> LDS nonzero list.
// Phase B: distributed feature eval + butterfly reduce.
// Phase C: matvec from LDS-cached w2, write bf16.
// ---------------------------------------------------------------------------
__global__ void h0_kernel(const float* __restrict__ init_m,
                          const float* __restrict__ w1, const float* __restrict__ b1,
                          const float* __restrict__ w2, const float* __restrict__ b2,
                          bf16_t* __restrict__ h) {
    __shared__ float w2s[16][256];     // 16 KB
    __shared__ int   list[1024];
    __shared__ int   count;
    __shared__ float fred[4][16];
    __shared__ float ftot[16];
    int i = blockIdx.x;
    int t = threadIdx.x;

    // cache w2 in LDS (coalesced, conflict-free reads later)
#pragma unroll
    for (int k = 0; k < 16; ++k) w2s[k][t] = w2[k * D_DIM + t];
    if (t == 0) count = 0;
    __syncthreads();

    // Phase A: scan row, collect nonzero column indices
    const float4* rowp = (const float4*)(init_m + (size_t)i * S_COLS);
#pragma unroll
    for (int p = 0; p < 4; ++p) {
        int v4 = t + p * 256;
        float4 v = rowp[v4];
        int jbase = v4 * 4;
        if (v.x != 0.f) { int idx = atomicAdd(&count, 1); list[idx] = jbase;     }
        if (v.y != 0.f) { int idx = atomicAdd(&count, 1); list[idx] = jbase + 1; }
        if (v.z != 0.f) { int idx = atomicAdd(&count, 1); list[idx] = jbase + 2; }
        if (v.w != 0.f) { int idx = atomicAdd(&count, 1); list[idx] = jbase + 3; }
    }
    __syncthreads();
    int cnt = count;

    // Phase B: feature sums over the list (threads stride the list)
    float lw1[16], lb1[16];
#pragma unroll
    for (int k = 0; k < 16; ++k) { lw1[k] = w1[k]; lb1[k] = b1[k]; }
    float f[16] = {};
    for (int q = t; q < cnt; q += 256) {
        float jf = (float)list[q];
#pragma unroll
        for (int k = 0; k < 16; ++k)
            f[k] += fmaxf(jf * lw1[k] + lb1[k], 0.f);
    }
    // wave butterfly reduce (64 lanes)
#pragma unroll
    for (int k = 0; k < 16; ++k) {
#pragma unroll
        for (int off = 32; off > 0; off >>= 1)
            f[k] += __shfl_xor(f[k], off, 64);
    }
    int wave = t >> 6, lane = t & 63;
    if (lane == 0) {
#pragma unroll
        for (int k = 0; k < 16; ++k) fred[wave][k] = f[k];
    }
    __syncthreads();
    if (t < 16) ftot[t] = fred[0][t] + fred[1][t] + fred[2][t] + fred[3][t];
    __syncthreads();

    // Phase C: matvec + mean, write bf16
    float cf = (float)cnt;
    float acc = cf * b2[t];
#pragma unroll
    for (int k = 0; k < 16; ++k) acc += ftot[k] * w2s[k][t];
    h[(size_t)i * D_DIM + t] = f2bf(acc / fmaxf(cf, 1.f));
}

// ---------------------------------------------------------------------------
// CSC build (once per launch): counting sort of edges by destination col.
// ---------------------------------------------------------------------------
__global__ void count_kernel(const int* __restrict__ eidx, int* __restrict__ cnt) {
    int e = blockIdx.x * 256 + threadIdx.x;
    if (e < E_EDGES) atomicAdd(&cnt[eidx[E_EDGES + e]], 1);
}

__global__ void scan_kernel(const int* __restrict__ cnt, int* __restrict__ offs,
                            int* __restrict__ cur) {
    __shared__ int sdata[1024];
    int t = threadIdx.x;
    int base = t * 20;
    int vals[20];
    int local = 0;
#pragma unroll
    for (int k = 0; k < 20; ++k) {
        int idx = base + k;
        int v = (idx < N_NODES) ? cnt[idx] : 0;
        vals[k] = local;
        local += v;
    }
    sdata[t] = local;
    __syncthreads();
    for (int off = 1; off < 1024; off <<= 1) {
        int v = (t >= off) ? sdata[t - off] : 0;
        __syncthreads();
        sdata[t] += v;
        __syncthreads();
    }
    int prefix = (t == 0) ? 0 : sdata[t - 1];
#pragma unroll
    for (int k = 0; k < 20; ++k) {
        int idx = base + k;
        if (idx < N_NODES) {
            int o = prefix + vals[k];
            offs[idx] = o;
            cur[idx]  = o;
        }
    }
    if (t == 1023) offs[N_NODES] = sdata[1023];
}

__global__ void fill_kernel(const int* __restrict__ eidx, const float* __restrict__ attr,
                            int* __restrict__ cur, int* __restrict__ src_s,
                            float* __restrict__ attr_s) {
    int e = blockIdx.x * 256 + threadIdx.x;
    if (e < E_EDGES) {
        int r = eidx[e];
        int c = eidx[E_EDGES + e];
        int pos = atomicAdd(&cur[c], 1);
        src_s[pos]  = r;
        attr_s[pos] = attr[e];
    }
}

// ---------------------------------------------------------------------------
// K2: gather — agg[c] = sum_{e into c} h[src[e]] * attr[e]; h is bf16.
// One wave per destination node; lane handles 4 channels (ushort4 = 8B).
// Unrolled by 2 edges for MLP. No atomics; agg written once, fp32.
// ---------------------------------------------------------------------------
__global__ void gather_kernel(const bf16_t* __restrict__ h, const int* __restrict__ offs,
                              const int* __restrict__ src_s, const float* __restrict__ attr_s,
                              float* __restrict__ agg) {
    int wave = (blockIdx.x * blockDim.x + threadIdx.x) >> 6;
    int lane = threadIdx.x & 63;
    if (wave >= N_NODES) return;
    int c  = wave;
    int e0 = offs[c], e1 = offs[c + 1];
    float4 acc = {0.f, 0.f, 0.f, 0.f};
    int e = e0;
    for (; e + 1 < e1; e += 2) {
        int   r0 = src_s[e],     r1 = src_s[e + 1];
        float a0 = attr_s[e],    a1 = attr_s[e + 1];
        ushort4 v0 = ((const ushort4*)(h + (size_t)r0 * D_DIM))[lane];
        ushort4 v1 = ((const ushort4*)(h + (size_t)r1 * D_DIM))[lane];
        acc.x += bf2f(v0.x) * a0;  acc.y += bf2f(v0.y) * a0;
        acc.z += bf2f(v0.z) * a0;  acc.w += bf2f(v0.w) * a0;
        acc.x += bf2f(v1.x) * a1;  acc.y += bf2f(v1.y) * a1;
        acc.z += bf2f(v1.z) * a1;  acc.w += bf2f(v1.w) * a1;
    }
    if (e < e1) {
        int   r = src_s[e];
        float a = attr_s[e];
        ushort4 v = ((const ushort4*)(h + (size_t)r * D_DIM))[lane];
        acc.x += bf2f(v.x) * a;  acc.y += bf2f(v.y) * a;
        acc.z += bf2f(v.z) * a;  acc.w += bf2f(v.w) * a;
    }
    ((float4*)(agg + (size_t)c * D_DIM))[lane] = acc;
}

// ---------------------------------------------------------------------------
// K3: C = relu(A @ B), A [M x 256] fp32, B [256 x 256] fp32.
// 64x64 tile / 256-thread block, 4x4 register tile, BK=16.
// Epilogue: bf16 to hdst (intermediate layers) or fp32 to fdst (final).
// ---------------------------------------------------------------------------
__global__ void gemm_relu_kernel(const float* __restrict__ A, const float* __restrict__ B,
                                 float* __restrict__ fdst, bf16_t* __restrict__ hdst, int M) {
    __shared__ float As[16][64];
    __shared__ float Bs[16][64];
    int t  = threadIdx.x;
    int tx = t & 15, ty = t >> 4;
    int bm = blockIdx.x * 64;
    int bn = blockIdx.y * 64;
    float acc[4][4] = {};
    for (int k0 = 0; k0 < 256; k0 += 16) {
#pragma unroll
        for (int p = 0; p < 4; ++p) {
            int row = p * 16 + ty;
            int m   = bm + row;
            As[tx][row] = (m < M) ? A[(size_t)m * 256 + k0 + tx] : 0.f;
        }
#pragma unroll
        for (int p = 0; p < 4; ++p) {
            int kk = p * 4 + (t >> 6);
            int n  = t & 63;
            Bs[kk][n] = B[(size_t)(k0 + kk) * 256 + bn + n];
        }
        __syncthreads();
#pragma unroll
        for (int kk = 0; kk < 16; ++kk) {
            float4 a4 = *(const float4*)&As[kk][ty * 4];
            float4 b4 = *(const float4*)&Bs[kk][tx * 4];
            float av[4] = {a4.x, a4.y, a4.z, a4.w};
            float bv[4] = {b4.x, b4.y, b4.z, b4.w};
#pragma unroll
            for (int i = 0; i < 4; ++i)
#pragma unroll
                for (int j = 0; j < 4; ++j)
                    acc[i][j] += av[i] * bv[j];
        }
        __syncthreads();
    }
#pragma unroll
    for (int i = 0; i < 4; ++i) {
        int m = bm + ty * 4 + i;
        if (m < M) {
            float r0 = fmaxf(acc[i][0], 0.f);
            float r1 = fmaxf(acc[i][1], 0.f);
            float r2 = fmaxf(acc[i][2], 0.f);
            float r3 = fmaxf(acc[i][3], 0.f);
            if (hdst) {
                ushort4 o = { f2bf(r0), f2bf(r1), f2bf(r2), f2bf(r3) };
                *(ushort4*)(hdst + (size_t)m * 256 + bn + tx * 4) = o;
            } else {
                float4 o = { r0, r1, r2, r3 };
                *(float4*)(fdst + (size_t)m * 256 + bn + tx * 4) = o;
            }
        }
    }
}

extern "C" void kernel_launch(void* const* d_in, const int* in_sizes, int n_in,
                              void* d_out, int out_size, void* d_ws, size_t ws_size,
                              hipStream_t stream) {
    const float* init_m = (const float*)d_in[0];
    const int*   eidx   = (const int*)  d_in[1];
    const float* attr   = (const float*)d_in[2];
    const float* w1     = (const float*)d_in[3];
    const float* b1     = (const float*)d_in[4];
    const float* w2     = (const float*)d_in[5];
    const float* b2     = (const float*)d_in[6];
    const float* Wm     = (const float*)d_in[7];
    float* out = (float*)d_out;

    // Workspace layout (bytes, 16-aligned):
    char* ws = (char*)d_ws;
    bf16_t* hbuf   = (bf16_t*)ws;                       // 10,240,000
    float*  aggbuf = (float*) (ws + 10240000);          // 20,480,000
    int*    cnt    = (int*)   (ws + 30720000);          // 80,000
    int*    offs   = (int*)   (ws + 30800000);          // 80,004
    int*    cur    = (int*)   (ws + 30880016);          // 80,000
    int*    src_s  = (int*)   (ws + 30960016);          // 2,560,000
    float*  attr_s = (float*) (ws + 33520016);          // 2,560,000  -> ~36.1 MB

    // --- CSC build (counting sort by destination col) ---
    hipMemsetAsync(cnt, 0, (size_t)N_NODES * sizeof(int), stream);
    count_kernel<<<(E_EDGES + 255) / 256, 256, 0, stream>>>(eidx, cnt);
    scan_kernel<<<1, 1024, 0, stream>>>(cnt, offs, cur);
    fill_kernel<<<(E_EDGES + 255) / 256, 256, 0, stream>>>(eidx, attr, cur, src_s, attr_s);

    // --- Projection (fused, no phi table) ---
    h0_kernel<<<N_NODES, 256, 0, stream>>>(init_m, w1, b1, w2, b2, hbuf);

    // --- 3x GCN layer: gather (bf16 reads, no atomics) + GEMM+ReLU ---
    for (int it = 0; it < 3; ++it) {
        gather_kernel<<<(N_NODES * 64 + 255) / 256, 256, 0, stream>>>(hbuf, offs, src_s, attr_s, aggbuf);
        dim3 grid((N_NODES + 63) / 64, 4);
        if (it == 2)
            gemm_relu_kernel<<<grid, 256, 0, stream>>>(aggbuf, Wm, out, (bf16_t*)nullptr, N_NODES);
        else
            gemm_relu_kernel<<<grid, 256, 0, stream>>>(aggbuf, Wm, (float*)nullptr, hbuf, N_NODES);
    }
}

// Round 4
// 821.591 us; speedup vs baseline: 8.6115x; 1.0636x over previous
//
#include <hip/hip_runtime.h>

#define N_NODES 20000
#define S_COLS  4096
#define E_EDGES 640000
#define D_DIM   256

typedef unsigned short bf16_t;
typedef __attribute__((ext_vector_type(8))) short short8;
typedef __attribute__((ext_vector_type(4))) float f32x4;

__device__ __forceinline__ float bf2f(bf16_t u) {
    union { unsigned int i; float f; } v; v.i = ((unsigned int)u) << 16; return v.f;
}
__device__ __forceinline__ bf16_t f2bf(float x) {   // round-to-nearest-even
    union { float f; unsigned int i; } v; v.f = x;
    unsigned int r = v.i + 0x7FFF + ((v.i >> 16) & 1);
    return (bf16_t)(r >> 16);
}
__device__ __forceinline__ float lo_bf(unsigned int u) {   // low bf16 of packed u32
    union { unsigned int i; float f; } v; v.i = u << 16; return v.f;
}
__device__ __forceinline__ float hi_bf(unsigned int u) {   // high bf16 of packed u32
    union { unsigned int i; float f; } v; v.i = u & 0xFFFF0000u; return v.f;
}
__device__ __forceinline__ unsigned int pack_bf(float a, float b) {
    return (unsigned int)f2bf(a) | ((unsigned int)f2bf(b) << 16);
}

// ---------------------------------------------------------------------------
// K1: h0[i] = (cnt*b2 + fsum @ w2) / max(cnt,1); fsum = 16-dim feature sum
// over nonzero column indices (rank-16 identity, no phi table).
// ---------------------------------------------------------------------------
__global__ void h0_kernel(const float* __restrict__ init_m,
                          const float* __restrict__ w1, const float* __restrict__ b1,
                          const float* __restrict__ w2, const float* __restrict__ b2,
                          bf16_t* __restrict__ h) {
    __shared__ float w2s[16][256];
    __shared__ int   list[1024];
    __shared__ int   count;
    __shared__ float fred[4][16];
    __shared__ float ftot[16];
    int i = blockIdx.x;
    int t = threadIdx.x;

#pragma unroll
    for (int k = 0; k < 16; ++k) w2s[k][t] = w2[k * D_DIM + t];
    if (t == 0) count = 0;
    __syncthreads();

    const float4* rowp = (const float4*)(init_m + (size_t)i * S_COLS);
#pragma unroll
    for (int p = 0; p < 4; ++p) {
        int v4 = t + p * 256;
        float4 v = rowp[v4];
        int jbase = v4 * 4;
        if (v.x != 0.f) { int idx = atomicAdd(&count, 1); list[idx] = jbase;     }
        if (v.y != 0.f) { int idx = atomicAdd(&count, 1); list[idx] = jbase + 1; }
        if (v.z != 0.f) { int idx = atomicAdd(&count, 1); list[idx] = jbase + 2; }
        if (v.w != 0.f) { int idx = atomicAdd(&count, 1); list[idx] = jbase + 3; }
    }
    __syncthreads();
    int cnt = count;

    float lw1[16], lb1[16];
#pragma unroll
    for (int k = 0; k < 16; ++k) { lw1[k] = w1[k]; lb1[k] = b1[k]; }
    float f[16] = {};
    for (int q = t; q < cnt; q += 256) {
        float jf = (float)list[q];
#pragma unroll
        for (int k = 0; k < 16; ++k)
            f[k] += fmaxf(jf * lw1[k] + lb1[k], 0.f);
    }
#pragma unroll
    for (int k = 0; k < 16; ++k) {
#pragma unroll
        for (int off = 32; off > 0; off >>= 1)
            f[k] += __shfl_xor(f[k], off, 64);
    }
    int wave = t >> 6, lane = t & 63;
    if (lane == 0) {
#pragma unroll
        for (int k = 0; k < 16; ++k) fred[wave][k] = f[k];
    }
    __syncthreads();
    if (t < 16) ftot[t] = fred[0][t] + fred[1][t] + fred[2][t] + fred[3][t];
    __syncthreads();

    float cf = (float)cnt;
    float acc = cf * b2[t];
#pragma unroll
    for (int k = 0; k < 16; ++k) acc += ftot[k] * w2s[k][t];
    h[(size_t)i * D_DIM + t] = f2bf(acc / fmaxf(cf, 1.f));
}

// ---------------------------------------------------------------------------
// CSC build (counting sort by destination col)
// ---------------------------------------------------------------------------
__global__ void count_kernel(const int* __restrict__ eidx, int* __restrict__ cnt) {
    int e = blockIdx.x * 256 + threadIdx.x;
    if (e < E_EDGES) atomicAdd(&cnt[eidx[E_EDGES + e]], 1);
}

__global__ void scan_kernel(const int* __restrict__ cnt, int* __restrict__ offs,
                            int* __restrict__ cur) {
    __shared__ int sdata[1024];
    int t = threadIdx.x;
    int base = t * 20;
    int vals[20];
    int local = 0;
#pragma unroll
    for (int k = 0; k < 20; ++k) {
        int idx = base + k;
        int v = (idx < N_NODES) ? cnt[idx] : 0;
        vals[k] = local;
        local += v;
    }
    sdata[t] = local;
    __syncthreads();
    for (int off = 1; off < 1024; off <<= 1) {
        int v = (t >= off) ? sdata[t - off] : 0;
        __syncthreads();
        sdata[t] += v;
        __syncthreads();
    }
    int prefix = (t == 0) ? 0 : sdata[t - 1];
#pragma unroll
    for (int k = 0; k < 20; ++k) {
        int idx = base + k;
        if (idx < N_NODES) {
            int o = prefix + vals[k];
            offs[idx] = o;
            cur[idx]  = o;
        }
    }
    if (t == 1023) offs[N_NODES] = sdata[1023];
}

__global__ void fill_kernel(const int* __restrict__ eidx, const float* __restrict__ attr,
                            int* __restrict__ cur, int* __restrict__ src_s,
                            float* __restrict__ attr_s) {
    int e = blockIdx.x * 256 + threadIdx.x;
    if (e < E_EDGES) {
        int r = eidx[e];
        int c = eidx[E_EDGES + e];
        int pos = atomicAdd(&cur[c], 1);
        src_s[pos]  = r;
        attr_s[pos] = attr[e];
    }
}

// ---------------------------------------------------------------------------
// W preprocessing: transpose to n-major and split fp32 -> bf16_hi + bf16_lo
// ---------------------------------------------------------------------------
__global__ void wsplit_kernel(const float* __restrict__ W,
                              bf16_t* __restrict__ Wt_hi, bf16_t* __restrict__ Wt_lo) {
    int k = blockIdx.x;    // 0..255
    int n = threadIdx.x;   // 0..255
    float w = W[k * D_DIM + n];
    bf16_t hi = f2bf(w);
    bf16_t lo = f2bf(w - bf2f(hi));
    Wt_hi[n * D_DIM + k] = hi;
    Wt_lo[n * D_DIM + k] = lo;
}

// ---------------------------------------------------------------------------
// K3: t = h @ W  (no relu), bf16 in/out, W = Wt_hi + Wt_lo (n-major).
// MFMA 16x16x32 bf16, no LDS: A/B fragments are contiguous 16B global loads.
// Block = 4 waves; wave w -> rows [bm + w*16, +16), cols [bn, bn+64).
// ---------------------------------------------------------------------------
__global__ void gemm_mfma_kernel(const bf16_t* __restrict__ h,
                                 const bf16_t* __restrict__ Wt_hi,
                                 const bf16_t* __restrict__ Wt_lo,
                                 bf16_t* __restrict__ t) {
    int w    = threadIdx.x >> 6;
    int lane = threadIdx.x & 63;
    int quad = lane >> 4;
    int id16 = lane & 15;
    int bm   = blockIdx.x * 64 + w * 16;
    int bn   = blockIdx.y * 64;

    f32x4 acc[4];
#pragma unroll
    for (int nt = 0; nt < 4; ++nt) acc[nt] = (f32x4){0.f, 0.f, 0.f, 0.f};

    const bf16_t* arow = h + (size_t)(bm + id16) * D_DIM;   // A[m=id16][k], k contiguous
#pragma unroll
    for (int k0 = 0; k0 < 256; k0 += 32) {
        short8 a = *(const short8*)(arow + k0 + quad * 8);
#pragma unroll
        for (int nt = 0; nt < 4; ++nt) {
            const bf16_t* brow = Wt_hi + (size_t)(bn + nt * 16 + id16) * D_DIM + k0 + quad * 8;
            const bf16_t* lrow = Wt_lo + (size_t)(bn + nt * 16 + id16) * D_DIM + k0 + quad * 8;
            short8 bh = *(const short8*)brow;
            short8 bl = *(const short8*)lrow;
            acc[nt] = __builtin_amdgcn_mfma_f32_16x16x32_bf16(a, bh, acc[nt], 0, 0, 0);
            acc[nt] = __builtin_amdgcn_mfma_f32_16x16x32_bf16(a, bl, acc[nt], 0, 0, 0);
        }
    }
    // C/D layout: col = lane&15, row = quad*4 + reg  [m89-verified]
#pragma unroll
    for (int nt = 0; nt < 4; ++nt) {
#pragma unroll
        for (int r = 0; r < 4; ++r) {
            int m = bm + quad * 4 + r;
            if (m < N_NODES)
                t[(size_t)m * D_DIM + bn + nt * 16 + id16] = f2bf(acc[nt][r]);
        }
    }
}

// ---------------------------------------------------------------------------
// K2: h_next[c] = relu( sum_{e into c} t[src[e]] * attr[e] )
// One wave per dest. Half-wave per edge (2 edges/iter), 16B row loads,
// cooperative (src,attr) staging + shfl broadcast, xor-32 final reduce.
// ---------------------------------------------------------------------------
__global__ void gather_relu_kernel(const bf16_t* __restrict__ t,
                                   const int* __restrict__ offs,
                                   const int* __restrict__ src_s,
                                   const float* __restrict__ attr_s,
                                   bf16_t* __restrict__ hdst, float* __restrict__ fdst) {
    int wid  = (blockIdx.x * blockDim.x + threadIdx.x) >> 6;
    int lane = threadIdx.x & 63;
    if (wid >= N_NODES) return;
    int half = lane >> 5;
    int l32  = lane & 31;
    int e0 = offs[wid], e1 = offs[wid + 1];

    float acc[8] = {};
    for (int base = e0; base < e1; base += 64) {
        int n = e1 - base; if (n > 64) n = 64;
        int   r_l = 0; float a_l = 0.f;
        if (lane < n) { r_l = src_s[base + lane]; a_l = attr_s[base + lane]; }
        for (int q = 0; q < n; q += 2) {
            int   sl = q + half;                 // half 0 -> edge q, half 1 -> edge q+1
            int   r  = __shfl(r_l, sl, 64);      // lanes >= n contribute a=0
            float a  = __shfl(a_l, sl, 64);
            uint4 v  = ((const uint4*)(t + (size_t)r * D_DIM))[l32];  // channels l32*8..+7
            acc[0] += lo_bf(v.x) * a;  acc[1] += hi_bf(v.x) * a;
            acc[2] += lo_bf(v.y) * a;  acc[3] += hi_bf(v.y) * a;
            acc[4] += lo_bf(v.z) * a;  acc[5] += hi_bf(v.z) * a;
            acc[6] += lo_bf(v.w) * a;  acc[7] += hi_bf(v.w) * a;
        }
    }
#pragma unroll
    for (int i = 0; i < 8; ++i) acc[i] += __shfl_xor(acc[i], 32, 64);

    if (half == 0) {
#pragma unroll
        for (int i = 0; i < 8; ++i) acc[i] = fmaxf(acc[i], 0.f);
        if (hdst) {
            uint4 o;
            o.x = pack_bf(acc[0], acc[1]);
            o.y = pack_bf(acc[2], acc[3]);
            o.z = pack_bf(acc[4], acc[5]);
            o.w = pack_bf(acc[6], acc[7]);
            ((uint4*)(hdst + (size_t)wid * D_DIM))[l32] = o;
        } else {
            float4 o0 = { acc[0], acc[1], acc[2], acc[3] };
            float4 o1 = { acc[4], acc[5], acc[6], acc[7] };
            float* dst = fdst + (size_t)wid * D_DIM + l32 * 8;
            *(float4*)dst       = o0;
            *(float4*)(dst + 4) = o1;
        }
    }
}

extern "C" void kernel_launch(void* const* d_in, const int* in_sizes, int n_in,
                              void* d_out, int out_size, void* d_ws, size_t ws_size,
                              hipStream_t stream) {
    const float* init_m = (const float*)d_in[0];
    const int*   eidx   = (const int*)  d_in[1];
    const float* attr   = (const float*)d_in[2];
    const float* w1     = (const float*)d_in[3];
    const float* b1     = (const float*)d_in[4];
    const float* w2     = (const float*)d_in[5];
    const float* b2     = (const float*)d_in[6];
    const float* Wm     = (const float*)d_in[7];
    float* out = (float*)d_out;

    // Workspace layout (bytes, 16-aligned). hbuf/tbuf have 16KB slack for the
    // GEMM m-overread (rows 20000..20031; poison bytes are finite bf16).
    char* ws = (char*)d_ws;
    bf16_t* hbuf   = (bf16_t*)ws;                        // 10,240,000 (+16K slack)
    bf16_t* tbuf   = (bf16_t*)(ws + 10256384);           // 10,240,000 (+16K slack)
    bf16_t* Wt_hi  = (bf16_t*)(ws + 20512768);           // 131,072
    bf16_t* Wt_lo  = (bf16_t*)(ws + 20643840);           // 131,072
    int*    cnt    = (int*)   (ws + 20774912);           // 80,000
    int*    offs   = (int*)   (ws + 20854912);           // 80,004
    int*    cur    = (int*)   (ws + 20934928);           // 80,000
    int*    src_s  = (int*)   (ws + 21014928);           // 2,560,000
    float*  attr_s = (float*) (ws + 23574928);           // 2,560,000  -> ~26.1 MB

    // --- CSC build ---
    hipMemsetAsync(cnt, 0, (size_t)N_NODES * sizeof(int), stream);
    count_kernel<<<(E_EDGES + 255) / 256, 256, 0, stream>>>(eidx, cnt);
    scan_kernel<<<1, 1024, 0, stream>>>(cnt, offs, cur);
    fill_kernel<<<(E_EDGES + 255) / 256, 256, 0, stream>>>(eidx, attr, cur, src_s, attr_s);

    // --- W transpose + hi/lo split ---
    wsplit_kernel<<<D_DIM, D_DIM, 0, stream>>>(Wm, Wt_hi, Wt_lo);

    // --- Projection ---
    h0_kernel<<<N_NODES, 256, 0, stream>>>(init_m, w1, b1, w2, b2, hbuf);

    // --- 3x GCN layer, reordered: t = h@W (MFMA), then h' = relu(gather(t)) ---
    dim3 ggrid((N_NODES * 64 + 255) / 256);
    dim3 mgrid((N_NODES + 63) / 64, 4);
    for (int it = 0; it < 3; ++it) {
        gemm_mfma_kernel<<<mgrid, 256, 0, stream>>>(hbuf, Wt_hi, Wt_lo, tbuf);
        if (it == 2)
            gather_relu_kernel<<<ggrid, 256, 0, stream>>>(tbuf, offs, src_s, attr_s,
                                                          (bf16_t*)nullptr, out);
        else
            gather_relu_kernel<<<ggrid, 256, 0, stream>>>(tbuf, offs, src_s, attr_s,
                                                          hbuf, (float*)nullptr);
    }
}